// Round 4
// baseline (26860.284 us; speedup 1.0000x reference)
//
#include <hip/hip_runtime.h>
#include <math.h>

// LSTM B=64 T=512 D=512 H=512, fp32 in/out.
// z = [h,x]@W + b; f,i,o,cb = split(z,4); c' = sig(f)c + sig(i)cb; h' = sig(o)c'
//
// R4: Zx = x@Wx + b precomputed (fp32 tiled GEMM, T-chunks of 64);
// recurrent h@Wh via 3-way split-f16 MFMA (hi + mid/2^11 + lo/2^22, 6 passes,
// ~33-bit product precision ~ fp32); h parity-double-buffered (fixes R3 race);
// persistent-per-chunk kernel with two-line grid barrier.
// Permuted gate cols: p = cg*32 + g*8 + hc  <->  orig col = g*512 + cg*8 + hc.

typedef _Float16 h8 __attribute__((ext_vector_type(8)));
typedef float f4 __attribute__((ext_vector_type(4)));

#define TC 64
#define S1 2048.0f            // 2^11 per split level
#define INV_S1 4.8828125e-4f  // 2^-11
#define INV_S2 2.384185791015625e-7f  // 2^-22

// ---- ws layout (float slots) ----
#define ZX_OFF    0u
#define ZX_F      (4096u*2048u)
#define WXP_OFF   (ZX_OFF + ZX_F)
#define WXP_F     (512u*2048u)
#define BP_OFF    (WXP_OFF + WXP_F)
#define BP_F      2048u
#define CBUF_OFF  (BP_OFF + BP_F)
#define CBUF_F    32768u
#define HS_OFF    (CBUF_OFF + CBUF_F)      // h splits f16 [2 par][3 split][64*512]
#define HS_F      (2u*3u*32768u/2u)        // 98304 float-slots
#define SYNC_OFF  (HS_OFF + HS_F)
#define SYNC_F    64u
#define WHS_OFF   (SYNC_OFF + SYNC_F)      // Wh splits f16 [64 cg][3][32 n][512 k]
#define WHS_F     (64u*3u*32u*512u/2u)     // 1572864 float-slots

__global__ __launch_bounds__(256) void zero_ws(float* __restrict__ p, int n) {
    int i = blockIdx.x * 256 + threadIdx.x;
    if (i < n) p[i] = 0.0f;
}

// Whs[cg][split][n][k], n = g*8+hc <-> W[k][g*512 + cg*8 + hc], k=0..511
__global__ __launch_bounds__(256) void prep_whs(const float* __restrict__ W,
                                                _Float16* __restrict__ Whs) {
    int cg = blockIdx.x >> 5;
    int n  = blockIdx.x & 31;
    int g = n >> 3, hc = n & 7;
    int col = g * 512 + cg * 8 + hc;
    size_t base = (size_t)cg * 49152 + (size_t)n * 512;
    for (int it = 0; it < 2; ++it) {
        int k = it * 256 + threadIdx.x;
        float w = W[(size_t)k * 2048 + col];
        _Float16 hi = (_Float16)w;
        float r1 = w - (float)hi;
        _Float16 mid = (_Float16)(r1 * S1);
        float r2 = r1 - (float)mid * INV_S1;
        _Float16 lo = (_Float16)(r2 * S1 * S1);
        Whs[base + k] = hi;
        Whs[base + 16384 + k] = mid;
        Whs[base + 32768 + k] = lo;
    }
}

// Wxp[k][p] = W[512+k][orig(p)]
__global__ __launch_bounds__(256) void prep_wxp(const float* __restrict__ W,
                                                float* __restrict__ Wxp) {
    int k = blockIdx.x;
    for (int it = 0; it < 8; ++it) {
        int p = it * 256 + threadIdx.x;
        int cg = p >> 5, r5 = p & 31, g = r5 >> 3, hc = r5 & 7;
        Wxp[(size_t)k * 2048 + p] = W[(size_t)(512 + k) * 2048 + (g * 512 + cg * 8 + hc)];
    }
}

__global__ __launch_bounds__(256) void prep_bp(const float* __restrict__ b,
                                               float* __restrict__ bp) {
    int p = blockIdx.x * 256 + threadIdx.x;
    int cg = p >> 5, r5 = p & 31, g = r5 >> 3, hc = r5 & 7;
    bp[p] = b[g * 512 + cg * 8 + hc];
}

// Zx chunk GEMM (fp32): rows r=tcc*64+b, 4096 x 512 x 2048, tile 128x256.
__global__ __launch_bounds__(256, 2) void zx_gemm(
    const float* __restrict__ x, const float* __restrict__ Wxp,
    const float* __restrict__ bp, float* __restrict__ Zx, int t0)
{
    __shared__ float As[2][8 * 132];
    __shared__ float Bs[2][8 * 260];
    const int tid = threadIdx.x;
    const int mb = blockIdx.x;
    const int nb = blockIdx.y;
    const int tm = tid & 15, tn = tid >> 4;
    const int m0 = tm * 8, n0 = tn * 16;

    const int skk = tid & 7;
    const int sm_ = tid >> 3;
    size_t gA[4];
#pragma unroll
    for (int it = 0; it < 4; ++it) {
        int r = mb * 128 + it * 32 + sm_;
        gA[it] = ((size_t)((r & 63) * 512 + t0 + (r >> 6))) * 512 + skk;
    }
    const int bkk = tid >> 6;
    const int bn  = (tid & 63) * 4;
    size_t gB0 = (size_t)bkk * 2048 + nb * 256 + bn;

    float acc[8][16];
#pragma unroll
    for (int i = 0; i < 8; ++i)
#pragma unroll
        for (int j = 0; j < 16; ++j) acc[i][j] = 0.0f;

    {
#pragma unroll
        for (int it = 0; it < 4; ++it)
            As[0][skk * 132 + it * 32 + sm_] = x[gA[it]];
#pragma unroll
        for (int it = 0; it < 2; ++it)
            *(float4*)&Bs[0][(it * 4 + bkk) * 260 + bn] =
                *(const float4*)&Wxp[gB0 + (size_t)it * 4 * 2048];
    }
    __syncthreads();

    for (int c = 0; c < 64; ++c) {
        float pa[4];
        float4 pb[2];
        if (c < 63) {
            int k0 = (c + 1) * 8;
#pragma unroll
            for (int it = 0; it < 4; ++it) pa[it] = x[gA[it] + k0];
#pragma unroll
            for (int it = 0; it < 2; ++it)
                pb[it] = *(const float4*)&Wxp[gB0 + (size_t)(k0 + it * 4) * 2048];
        }
        const float* Ac = As[c & 1];
        const float* Bc = Bs[c & 1];
#pragma unroll
        for (int kk = 0; kk < 8; ++kk) {
            float4 a0 = *(const float4*)&Ac[kk * 132 + m0];
            float4 a1 = *(const float4*)&Ac[kk * 132 + m0 + 4];
            float4 b0 = *(const float4*)&Bc[kk * 260 + n0];
            float4 b1 = *(const float4*)&Bc[kk * 260 + n0 + 4];
            float4 b2 = *(const float4*)&Bc[kk * 260 + n0 + 8];
            float4 b3 = *(const float4*)&Bc[kk * 260 + n0 + 12];
            float av[8] = {a0.x,a0.y,a0.z,a0.w,a1.x,a1.y,a1.z,a1.w};
            float bv[16] = {b0.x,b0.y,b0.z,b0.w,b1.x,b1.y,b1.z,b1.w,
                            b2.x,b2.y,b2.z,b2.w,b3.x,b3.y,b3.z,b3.w};
#pragma unroll
            for (int i = 0; i < 8; ++i)
#pragma unroll
                for (int j = 0; j < 16; ++j)
                    acc[i][j] += av[i] * bv[j];
        }
        if (c < 63) {
            int nbuf = (c + 1) & 1;
#pragma unroll
            for (int it = 0; it < 4; ++it)
                As[nbuf][skk * 132 + it * 32 + sm_] = pa[it];
#pragma unroll
            for (int it = 0; it < 2; ++it)
                *(float4*)&Bs[nbuf][(it * 4 + bkk) * 260 + bn] = pb[it];
            __syncthreads();
        }
    }

    float bb[16];
#pragma unroll
    for (int j = 0; j < 4; ++j)
        *(float4*)&bb[j * 4] = *(const float4*)&bp[nb * 256 + n0 + j * 4];
#pragma unroll
    for (int i = 0; i < 8; ++i) {
        float* dst = Zx + (size_t)(mb * 128 + tm * 8 + i) * 2048 + nb * 256 + n0;
#pragma unroll
        for (int j = 0; j < 4; ++j)
            *(float4*)(dst + j * 4) = make_float4(
                acc[i][j*4+0] + bb[j*4+0], acc[i][j*4+1] + bb[j*4+1],
                acc[i][j*4+2] + bb[j*4+2], acc[i][j*4+3] + bb[j*4+3]);
    }
}

// Recurrent chunk: grid (64 cg, 4 sg), 256 thr. 3-way split-f16 MFMA h@Wh.
__global__ __launch_bounds__(256, 1) void lstm_rec(
    const float* __restrict__ Zx, const _Float16* __restrict__ Whs,
    float* __restrict__ out, _Float16* __restrict__ hs,
    float* __restrict__ cbuf, unsigned* __restrict__ sync, int t0)
{
    __shared__ _Float16 Wls[3][32 * 520];   // 99840 B
    __shared__ _Float16 Als[3][16 * 520];   // 49920 B
    __shared__ float zpart[4 * 528];        // 8448 B, stride 33

    const int tid = threadIdx.x;
    const int cg = blockIdx.x, sg = blockIdx.y;

    // ---- load W splits into LDS (once per chunk): 6144 uint4 ----
    {
        const uint4* src = (const uint4*)(Whs + (size_t)cg * 49152);
#pragma unroll
        for (int it = 0; it < 24; ++it) {
            int idx = it * 256 + tid;            // 0..6143
            int split = idx >> 11;               // 2048 uint4 per split
            int n = (idx & 2047) >> 6;
            int kc = idx & 63;
            uint4 v = src[split * 2048 + n * 64 + kc];
            *(uint4*)(&Wls[split][n * 520 + kc * 8]) = v;
        }
    }

    const int es = tid >> 3, ehc = tid & 7;
    float creg = 0.0f;
    if (tid < 128)
        creg = cbuf[(sg * 16 + es) * 512 + cg * 8 + ehc];

    const int lane = tid & 63;
    const int w = tid >> 6;
    const int mrow = lane & 15;
    const int q = lane >> 4;

    __syncthreads();

    for (int tc = 0; tc < TC; ++tc) {
        const int t = t0 + tc;
        const int pr = t & 1, pw = (t + 1) & 1;

        // ---- stage A = h splits (read parity pr): 3072 uint4 ----
#pragma unroll
        for (int it = 0; it < 12; ++it) {
            int idx = it * 256 + tid;            // 0..3071
            int split = idx >> 10;               // 1024 uint4 per split
            int row = (idx & 1023) >> 6;
            int kc = idx & 63;
            uint4 v = *(const uint4*)(hs + ((size_t)(pr * 3 + split)) * 32768
                                         + (sg * 16 + row) * 512 + kc * 8);
            *(uint4*)(&Als[split][row * 520 + kc * 8]) = v;
        }
        // prefetch Zx gate values
        float zxv[4];
        if (tid < 128) {
            size_t zb = ((size_t)(tc * 64) + sg * 16 + es) * 2048 + cg * 32;
#pragma unroll
            for (int g = 0; g < 4; ++g) zxv[g] = Zx[zb + g * 8 + ehc];
        }
        __syncthreads();

        // ---- 6-pass MFMA: wave w -> k-tiles w*4..w*4+3 ----
        f4 acc0[2] = {{0,0,0,0},{0,0,0,0}};
        f4 acc1[2] = {{0,0,0,0},{0,0,0,0}};
        f4 acc2[2] = {{0,0,0,0},{0,0,0,0}};
#pragma unroll
        for (int i = 0; i < 4; ++i) {
            int kb = (w * 4 + i) * 32 + q * 8;
            h8 ahi = *(const h8*)(&Als[0][mrow * 520 + kb]);
            h8 ami = *(const h8*)(&Als[1][mrow * 520 + kb]);
            h8 alo = *(const h8*)(&Als[2][mrow * 520 + kb]);
#pragma unroll
            for (int nt = 0; nt < 2; ++nt) {
                int brow = (nt * 16 + mrow) * 520 + kb;
                h8 bhi = *(const h8*)(&Wls[0][brow]);
                h8 bmi = *(const h8*)(&Wls[1][brow]);
                h8 blo = *(const h8*)(&Wls[2][brow]);
                acc0[nt] = __builtin_amdgcn_mfma_f32_16x16x32_f16(ahi, bhi, acc0[nt], 0, 0, 0);
                acc1[nt] = __builtin_amdgcn_mfma_f32_16x16x32_f16(ahi, bmi, acc1[nt], 0, 0, 0);
                acc1[nt] = __builtin_amdgcn_mfma_f32_16x16x32_f16(ami, bhi, acc1[nt], 0, 0, 0);
                acc2[nt] = __builtin_amdgcn_mfma_f32_16x16x32_f16(ahi, blo, acc2[nt], 0, 0, 0);
                acc2[nt] = __builtin_amdgcn_mfma_f32_16x16x32_f16(alo, bhi, acc2[nt], 0, 0, 0);
                acc2[nt] = __builtin_amdgcn_mfma_f32_16x16x32_f16(ami, bmi, acc2[nt], 0, 0, 0);
            }
        }
#pragma unroll
        for (int nt = 0; nt < 2; ++nt)
#pragma unroll
            for (int r = 0; r < 4; ++r) {
                int s = q * 4 + r;
                zpart[w * 528 + s * 33 + nt * 16 + mrow] =
                    acc0[nt][r] + acc1[nt][r] * INV_S1 + acc2[nt][r] * INV_S2;
            }
        __syncthreads();

        // ---- epilogue ----
        if (tid < 128) {
            float z[4];
#pragma unroll
            for (int g = 0; g < 4; ++g) {
                float s = zxv[g];
#pragma unroll
                for (int ww = 0; ww < 4; ++ww)
                    s += zpart[ww * 528 + es * 33 + g * 8 + ehc];
                z[g] = s;
            }
            float sf = 1.0f / (1.0f + expf(-z[0]));
            float si = 1.0f / (1.0f + expf(-z[1]));
            float so = 1.0f / (1.0f + expf(-z[2]));
            creg = sf * creg + si * z[3];
            float h = so * creg;
            int brow = sg * 16 + es, colb = cg * 8 + ehc;
            out[((size_t)brow * 512 + t) * 512 + colb] = h;
            _Float16 hi = (_Float16)h;
            float r1 = h - (float)hi;
            _Float16 mid = (_Float16)(r1 * S1);
            float r2 = r1 - (float)mid * INV_S1;
            _Float16 lo = (_Float16)(r2 * S1 * S1);
            size_t hb = brow * 512 + colb;
            hs[((size_t)(pw * 3 + 0)) * 32768 + hb] = hi;
            hs[((size_t)(pw * 3 + 1)) * 32768 + hb] = mid;
            hs[((size_t)(pw * 3 + 2)) * 32768 + hb] = lo;
        }

        // ---- grid barrier (skip on last step of chunk) ----
        if (tc < TC - 1) {
            __threadfence();
            __syncthreads();
            if (tid == 0) {
                unsigned old = __hip_atomic_fetch_add(&sync[0], 1u, __ATOMIC_RELEASE,
                                                      __HIP_MEMORY_SCOPE_AGENT);
                unsigned want = (unsigned)(t + 1);
                if (old == 255u) {
                    __hip_atomic_store(&sync[0], 0u, __ATOMIC_RELAXED,
                                       __HIP_MEMORY_SCOPE_AGENT);
                    __hip_atomic_store(&sync[32], want, __ATOMIC_RELEASE,
                                       __HIP_MEMORY_SCOPE_AGENT);
                } else {
                    while (__hip_atomic_load(&sync[32], __ATOMIC_ACQUIRE,
                                             __HIP_MEMORY_SCOPE_AGENT) < want)
                        __builtin_amdgcn_s_sleep(2);
                }
            }
            __syncthreads();
        }
    }

    if (tid < 128)
        cbuf[(sg * 16 + es) * 512 + cg * 8 + ehc] = creg;
}

extern "C" void kernel_launch(void* const* d_in, const int* in_sizes, int n_in,
                              void* d_out, int out_size, void* d_ws, size_t ws_size,
                              hipStream_t stream) {
    const float* x = (const float*)d_in[0];
    const float* W = (const float*)d_in[1];
    const float* b = (const float*)d_in[2];
    float* out = (float*)d_out;
    float* ws = (float*)d_ws;

    float*     Zx   = ws + ZX_OFF;
    float*     Wxp  = ws + WXP_OFF;
    float*     bp   = ws + BP_OFF;
    float*     cbuf = ws + CBUF_OFF;
    _Float16*  hs   = (_Float16*)(ws + HS_OFF);
    unsigned*  sync = (unsigned*)(ws + SYNC_OFF);
    _Float16*  Whs  = (_Float16*)(ws + WHS_OFF);

    // zero c-state, h splits (both parities), sync vars
    zero_ws<<<(CBUF_F + HS_F + SYNC_F + 255) / 256, 256, 0, stream>>>(
        ws + CBUF_OFF, CBUF_F + HS_F + SYNC_F);
    prep_whs<<<2048, 256, 0, stream>>>(W, Whs);
    prep_wxp<<<512, 256, 0, stream>>>(W, Wxp);
    prep_bp<<<8, 256, 0, stream>>>(b, bp);

    for (int c = 0; c < 8; ++c) {
        int t0 = c * TC;
        zx_gemm<<<dim3(32, 8), 256, 0, stream>>>(x, Wxp, bp, Zx, t0);
        lstm_rec<<<dim3(64, 4), 256, 0, stream>>>(Zx, Whs, out, hs, cbuf, sync, t0);
    }
}